// Round 2
// baseline (125.600 us; speedup 1.0000x reference)
//
#include <hip/hip_runtime.h>

// SKA: per-pixel dynamic depthwise 5x5 conv
// x: [B=8, C=256, H=64, W=64] f32
// w: [B=8, G=8, K2=25, H=64, W=64] f32
// out[b,c,h,w] = sum_k x[b,c,h+k/5-2,w+k%5-2] * w[b,g,k,h,w], g = c/32
//
// Design G (round 9 = round-8 resubmit; round-8 bench was a container-level
// infra failure, no kernel verdict). One-shot block-shared staging + k-row
// weight pipeline.
// Round-7 diagnosis: 115us vs ~14-19us HBM floor / ~4us issue floor => ~95%
// stall. Causes: (a) 2 waves/SIMD occupancy cap with 100 weight VGPRs held
// all-kernel; (b) per-channel global->LDS->reg round trip serialized by the
// in-order DS pipe + wave_barriers, 8x per block; (c) weight OOB masking via
// 100 cndmasks.
// Fixes:
//  - Stage ALL 8 channels x 20-row window into LDS once (42.6 KB), ONE
//    __syncthreads, then pure compute. OOB rows staged as 0.0 and guard/pad
//    words zeroed => weights need NO masks (OOB taps multiply exact zero,
//    matching jnp.pad semantics bit-exactly).
//  - Pitch 68 + channel stride 1364 (both %4==0): every inner read is a
//    16B-aligned ds_read_b128 at the 8-clk bank floor (uniform 8 words/bank).
//  - Weights loaded per tap-row (5 quads), double-buffered: 40 VGPRs instead
//    of 100; prefetch of row di+1 hides under ~500 cy of row-di FMAs.
//  - __launch_bounds__(256,3): 3 blocks/CU (LDS 3x42.6=128KB ok), 12 waves/CU.
//  - XCD swizzle: chunk (blocks sharing identical w) in the SLOW blockIdx
//    bits => chunk partners land on the same XCD, w re-reads become L2 hits.
// SROA: static indexing only; float4 fields via .x/.y/.z/.w.
// Tripwire: WRITE_SIZE must stay 32768 KB (no scratch spill).

#define B_ 8
#define C_ 256
#define G_ 8
#define CG_ 32
#define H_ 64
#define W_ 64
#define K2_ 25
#define HW_ (H_ * W_)
#define NCH 8
#define NROWS 20          // 16-row band + 2 halo each side
#define PITCH 68          // LDS words per row: 2 guard + 64 data + 2 pad
#define CHSTRIDE 1364     // 2 + 20*68 = 1362, rounded up to %4==0

__global__ __launch_bounds__(256, 3) void ska_kernel(
    const float* __restrict__ x, const float* __restrict__ w,
    float* __restrict__ out) {
  __shared__ __align__(16) float lds[NCH * CHSTRIDE];  // 10912 words = 42.6 KB
  const int tid = threadIdx.x;
  const int lr = tid >> 4;   // output row within band (0..15)
  const int j = tid & 15;    // column quad (cols 4j..4j+3)
  const int wcol = j * 4;

  // blockIdx = [chunk(2) | b(3) | g(3) | band(2)] -- chunk slowest so the 4
  // blocks reading identical w stay on one XCD (blk%8 unchanged by chunk).
  const int blk = blockIdx.x;  // 1024 blocks
  const int band = blk & 3;
  const int g = (blk >> 2) & 7;
  const int b = (blk >> 5) & 7;
  const int chunk = blk >> 8;

  const int h0 = band * 16;
  const int h = h0 + lr;

  // ---- weight base; issue di=0 row of weights before staging (overlap) ----
  const float* wb =
      w + (size_t)(b * G_ + g) * K2_ * HW_ + (size_t)h * W_ + wcol;
  float4 wcur0 = *(const float4*)(wb + (size_t)0 * HW_);
  float4 wcur1 = *(const float4*)(wb + (size_t)1 * HW_);
  float4 wcur2 = *(const float4*)(wb + (size_t)2 * HW_);
  float4 wcur3 = *(const float4*)(wb + (size_t)3 * HW_);
  float4 wcur4 = *(const float4*)(wb + (size_t)4 * HW_);

  // ---- zero guard/pad words: per channel, words {0,1} + rows' {66..69} ----
  // 82 words/channel * 8 = 656 total.
#pragma unroll
  for (int it = 0; it < 3; ++it) {
    const int i = tid + it * 256;
    if (i < NCH * 82) {
      const int c = i / 82;             // constant div -> magic mul
      const int p = i - c * 82;
      const int word =
          (p < 2) ? p : (66 + ((p - 2) >> 2) * PITCH + ((p - 2) & 3));
      lds[c * CHSTRIDE + word] = 0.0f;
    }
  }

  // ---- stage x: 20-row window x 8 channels; OOB rows become exact 0 ----
  const size_t chan0 = (size_t)(b * C_ + g * CG_ + chunk * NCH) * HW_;
  const float* xc = x + chan0;
#pragma unroll
  for (int c = 0; c < NCH; ++c) {
#pragma unroll
    for (int it = 0; it < 2; ++it) {
      const int i = tid + it * 256;
      if (i < NROWS * 16) {             // 320 quads per channel
        const int rl = i >> 4;          // window row 0..19
        const int q = i & 15;           // column quad
        const int gr = h0 - 2 + rl;     // global row, may be OOB
        float4 v = make_float4(0.f, 0.f, 0.f, 0.f);
        if ((unsigned)gr < (unsigned)H_)
          v = *(const float4*)(xc + (size_t)c * HW_ + gr * W_ + q * 4);
        const int wo = c * CHSTRIDE + 2 + rl * PITCH + q * 4;  // 8B aligned
        *(float2*)&lds[wo] = make_float2(v.x, v.y);
        *(float2*)&lds[wo + 2] = make_float2(v.z, v.w);
      }
    }
  }

  __syncthreads();

  // ---- compute: di outer (weight row double-buffer), channels inner ----
  alignas(16) float acc[NCH][4];
#pragma unroll
  for (int c = 0; c < NCH; ++c) {
    acc[c][0] = 0.f; acc[c][1] = 0.f; acc[c][2] = 0.f; acc[c][3] = 0.f;
  }

  float4 wn0, wn1, wn2, wn3, wn4;
#pragma unroll
  for (int di = 0; di < 5; ++di) {
    if (di < 4) {  // prefetch next tap-row's 5 weight quads
      const size_t kb = (size_t)((di + 1) * 5) * HW_;
      wn0 = *(const float4*)(wb + kb + 0 * HW_);
      wn1 = *(const float4*)(wb + kb + 1 * HW_);
      wn2 = *(const float4*)(wb + kb + 2 * HW_);
      wn3 = *(const float4*)(wb + kb + 3 * HW_);
      wn4 = *(const float4*)(wb + kb + 4 * HW_);
    }
    // word rbase corresponds to col (wcol-2) of window row (lr+di); both
    // b128 reads 16B-aligned by construction (PITCH,CHSTRIDE,wcol %4==0).
    const int rbase = (lr + di) * PITCH + wcol;
#pragma unroll
    for (int c = 0; c < NCH; ++c) {
      alignas(16) float xr[8];
      *(float4*)&xr[0] = *(const float4*)&lds[c * CHSTRIDE + rbase];
      *(float4*)&xr[4] = *(const float4*)&lds[c * CHSTRIDE + rbase + 4];
#pragma unroll
      for (int dj = 0; dj < 5; ++dj) {
        const float4 wv = (dj == 0) ? wcur0
                        : (dj == 1) ? wcur1
                        : (dj == 2) ? wcur2
                        : (dj == 3) ? wcur3
                                    : wcur4;
        acc[c][0] = fmaf(xr[dj + 0], wv.x, acc[c][0]);
        acc[c][1] = fmaf(xr[dj + 1], wv.y, acc[c][1]);
        acc[c][2] = fmaf(xr[dj + 2], wv.z, acc[c][2]);
        acc[c][3] = fmaf(xr[dj + 3], wv.w, acc[c][3]);
      }
    }
    // rotate double-buffer (dead on di==4, DCE'd; full unroll renames)
    wcur0 = wn0; wcur1 = wn1; wcur2 = wn2; wcur3 = wn3; wcur4 = wn4;
  }

  float* ob = out + chan0 + (size_t)h * W_ + wcol;
#pragma unroll
  for (int c = 0; c < NCH; ++c)
    *(float4*)(ob + (size_t)c * HW_) = *(const float4*)acc[c];
}

extern "C" void kernel_launch(void* const* d_in, const int* in_sizes, int n_in,
                              void* d_out, int out_size, void* d_ws,
                              size_t ws_size, hipStream_t stream) {
  const float* x = (const float*)d_in[0];
  const float* w = (const float*)d_in[1];
  float* out = (float*)d_out;
  // grid: 4 chunks * 8 b * 8 g * 4 bands = 1024 blocks of 256 threads
  ska_kernel<<<dim3(1024), dim3(256), 0, stream>>>(x, w, out);
}